// Round 12
// baseline (1554.838 us; speedup 1.0000x reference)
//
#include <hip/hip_runtime.h>
#include <stdint.h>

// ---------------------------------------------------------------------------
// EdgeNodeGCN on MI355X (gfx950). Inputs fp32, edge_index int32, output fp32.
// SINGLE persistent kernel, phases separated by a device-scope grid barrier.
// R11 evidence: per-dispatch gap ~10-20us dominated (6 dispatches); all split
// kernels individually fast. 512 blocks x 512 thr, __launch_bounds__(512,4)
// -> VGPR<=128 -> 2 blocks/CU schedulable -> all blocks co-resident (no
// deadlock). Barrier: monotone phase numbers, per-block flags + release word,
// agent-scope atomics + __threadfence (wbL2/inv on gfx950 = cross-XCD safe).
// 0xAA poison reads as negative int -> always "not yet arrived" -> no memset.
//
// Phases:
//  0 convert (x->bf16, weights->col-major bf16, head=-1)
//  1 blocks[0,256): linked-list build (atomicExch); [256,512): GEMM1 -> T=P|Q
//  2 gather: 4 chains/wave, EA over P (cols 0-255), XA
//  3 gemm2: EA@Wd -> edges T[0..127] (in-block read-before-write, dead EA) ||
//    gemm_node: XA@Wn -> nodes T[256..511] (dead Q)   [same phase, no hazard]
//  4 final: h=[nodes|edges] @ Wf1 -> relu -> @W_f2 -> sigmoid -> out (fp32)
// ---------------------------------------------------------------------------

typedef short short8 __attribute__((ext_vector_type(8)));
typedef float f32x4 __attribute__((ext_vector_type(4)));
typedef float float4v __attribute__((ext_vector_type(4)));
typedef unsigned short us8 __attribute__((ext_vector_type(8)));
typedef unsigned short us4 __attribute__((ext_vector_type(4)));

__device__ inline float bf2f(unsigned short h) {
    union { unsigned int u; float f; } v;
    v.u = ((unsigned int)h) << 16;
    return v.f;
}
__device__ inline unsigned short f2bf(float f) {
    union { float f; unsigned int u; } v;
    v.f = f;
    unsigned int r = v.u + 0x7FFFu + ((v.u >> 16) & 1u);  // RNE
    return (unsigned short)(r >> 16);
}

__device__ inline void gridbar(int* flags, int* release, int phase) {
    __syncthreads();
    __threadfence();                          // release: wbL2 on gfx950
    if (blockIdx.x == 0) {
        if (threadIdx.x == 0)
            __hip_atomic_store(&flags[0], phase, __ATOMIC_RELEASE, __HIP_MEMORY_SCOPE_AGENT);
        for (int b = threadIdx.x; b < (int)gridDim.x; b += blockDim.x)
            if (b > 0)
                while (__hip_atomic_load(&flags[b], __ATOMIC_ACQUIRE, __HIP_MEMORY_SCOPE_AGENT) < phase) {}
        __syncthreads();
        if (threadIdx.x == 0)
            __hip_atomic_store(release, phase, __ATOMIC_RELEASE, __HIP_MEMORY_SCOPE_AGENT);
    } else {
        if (threadIdx.x == 0) {
            __hip_atomic_store(&flags[blockIdx.x], phase, __ATOMIC_RELEASE, __HIP_MEMORY_SCOPE_AGENT);
            while (__hip_atomic_load(release, __ATOMIC_ACQUIRE, __HIP_MEMORY_SCOPE_AGENT) < phase) {}
        }
    }
    __threadfence();                          // acquire: inv L1/L2
    __syncthreads();
}

__global__ __launch_bounds__(512, 4) void k_all(
    const float* __restrict__ x, const int* __restrict__ src,
    const int* __restrict__ dst,
    const float* __restrict__ W_node, const float* __restrict__ b_node,
    const float* __restrict__ W_edge, const float* __restrict__ b_edge,
    const float* __restrict__ W_ed, const float* __restrict__ b_ed,
    const float* __restrict__ W_f1, const float* __restrict__ b_f1,
    const float* __restrict__ W_f2, const float* __restrict__ b_f2,
    unsigned short* __restrict__ xb, unsigned short* __restrict__ WE2T,
    unsigned short* __restrict__ WnT, unsigned short* __restrict__ WdT,
    unsigned short* __restrict__ Wf1T,
    unsigned short* __restrict__ T, unsigned short* __restrict__ XA,
    int* __restrict__ head, unsigned long long* __restrict__ next2,
    int* flags, int* release,
    float* __restrict__ out, int N, int E)
{
    __shared__ unsigned short st[2][16 * 132];
    const int tid = threadIdx.x;
    const int nblk = gridDim.x;
    const int gthreads = nblk * 512;
    const int wave = tid >> 6;
    const int lane = tid & 63;
    const int quad = lane >> 4;
    const int col16 = lane & 15;
    const int row_tiles = (N + 15) / 16;
    const int srow = tid >> 5;                 // 0..15
    const int sc4 = (tid & 31) * 4;            // 0..124

    // ================= phase 0: convert + head init =================
    {
        const int quads = N * 32;              // N*128/4
        const int conv_items = quads + 143360 + N;
        for (int i = blockIdx.x * 512 + tid; i < conv_items; i += gthreads) {
            if (i < quads) {
                float4v v = ((const float4v*)x)[i];
                us4 o;
                for (int j = 0; j < 4; ++j) o[j] = f2bf(v[j]);
                ((us4*)xb)[i] = o;
                continue;
            }
            int j = i - quads;
            if (j < 65536) {                   // WE2T [512 c][128 k]
                int c = j & 511, k = j >> 9;
                float v;
                if (c < 256) v = W_edge[k * 256 + c] - W_edge[(k + 128) * 256 + c];
                else         v = W_edge[(k + 128) * 256 + (c - 256)];
                WE2T[c * 128 + k] = f2bf(v);
            } else if (j < 98304) {            // WnT [256 c][128 k]
                int t = j - 65536;
                int c = t & 255, k = t >> 8;
                WnT[c * 128 + k] = f2bf(W_node[k * 256 + c]);
            } else if (j < 131072) {           // WdT [128 c][256 k]
                int t = j - 98304;
                int c = t & 127, k = t >> 7;
                WdT[c * 256 + k] = f2bf(W_ed[k * 128 + c]);
            } else if (j < 143360) {           // Wf1T [32 c][384 k]
                int t = j - 131072;
                int c = t & 31, k = t >> 5;
                Wf1T[c * 384 + k] = f2bf(W_f1[k * 32 + c]);
            } else {
                int t = j - 143360;
                if (t < N) head[t] = -1;
            }
        }
    }
    gridbar(flags, release, 1);

    // ============ phase 1: list build (half) + GEMM1 (half) ============
    {
        const int HB = nblk >> 1;
        if ((int)blockIdx.x < HB) {
            for (int i = blockIdx.x * 512 + tid; i < E; i += HB * 512) {
                int s = src[i], d = dst[i];
                if ((unsigned)d < (unsigned)N && (unsigned)s < (unsigned)N) {
                    int old = atomicExch(&head[d], i);
                    next2[i] = ((unsigned long long)(unsigned)s << 32) | (unsigned)old;
                }
            }
        } else {
            const int row_groups = (row_tiles + 7) / 8;
            const int gemm_units = row_groups * 4;
            for (int g = blockIdx.x - HB; g < gemm_units; g += nblk - HB) {
                int gx = g >> 2, gy = g & 3;
                int lcol = wave * 16 + col16;  // 0..127
                int col = gy * 128 + lcol;     // 0..511
                float bias = (col < 256) ? b_edge[col] : 0.f;
                short8 bf[4];
                for (int ks = 0; ks < 4; ++ks)
                    bf[ks] = *(const short8*)(WE2T + (size_t)col * 128 + ks * 32 + quad * 8);
                for (int t = 0; t < 8; ++t) {
                    int tile = gx * 8 + t;
                    if (tile >= row_tiles) break;   // block-uniform
                    int r0 = tile * 16;
                    int arow = r0 + col16; if (arow >= N) arow = N - 1;
                    f32x4 acc = {0.f, 0.f, 0.f, 0.f};
                    const unsigned short* ap = xb + (size_t)arow * 128 + quad * 8;
                    for (int ks = 0; ks < 4; ++ks) {
                        short8 a = *(const short8*)(ap + ks * 32);
                        acc = __builtin_amdgcn_mfma_f32_16x16x32_bf16(a, bf[ks], acc, 0, 0, 0);
                    }
                    unsigned short* sb = st[t & 1];
                    for (int r = 0; r < 4; ++r)
                        sb[(quad * 4 + r) * 132 + lcol] = f2bf(acc[r] + bias);
                    __syncthreads();
                    if (r0 + srow < N) {
                        us4 v = *(const us4*)(sb + srow * 132 + sc4);
                        *(us4*)(T + (size_t)(r0 + srow) * 512 + gy * 128 + sc4) = v;
                    }
                }
            }
        }
    }
    gridbar(flags, release, 2);

    // ================= phase 2: gather (chain walk) =================
    {
        int qtr = lane >> 4;
        int c = lane & 15;
        int c16 = c * 16, c8 = c * 8;
        int stride = nblk * 32;               // 8 waves * 4 chains per block
        for (int n = blockIdx.x * 32 + wave * 4 + qtr; n < N; n += stride) {
            us8 pv0 = *(const us8*)(T + (size_t)n * 512 + c16);
            us8 pv1 = *(const us8*)(T + (size_t)n * 512 + c16 + 8);
            float p[16];
            for (int j = 0; j < 8; ++j) { p[j] = bf2f(pv0[j]); p[8 + j] = bf2f(pv1[j]); }
            float aE[16];
            for (int j = 0; j < 16; ++j) aE[j] = 0.f;
            float aX[8];
            for (int j = 0; j < 8; ++j) aX[j] = 0.f;

            int cur = head[n];
            unsigned long long e2 = (cur >= 0) ? next2[cur] : 0ull;
            while (cur >= 0) {
                int s = (int)(e2 >> 32);
                int nxt = (int)(unsigned)(e2 & 0xFFFFFFFFull);
                unsigned long long e2n = (nxt >= 0) ? next2[nxt] : 0ull;
                const unsigned short* tb = T + (size_t)s * 512 + 256;
                us8 q0 = *(const us8*)(tb + c16);
                us8 q1 = *(const us8*)(tb + c16 + 8);
                us8 xv = *(const us8*)(xb + (size_t)s * 128 + c8);
                for (int j = 0; j < 8; ++j) {
                    aE[j]     += fmaxf(p[j]     + bf2f(q0[j]), 0.f);
                    aE[8 + j] += fmaxf(p[8 + j] + bf2f(q1[j]), 0.f);
                    aX[j]     += bf2f(xv[j]);
                }
                cur = nxt; e2 = e2n;
            }
            us8 e0, e1, xo;
            for (int j = 0; j < 8; ++j) {
                e0[j] = f2bf(aE[j]);
                e1[j] = f2bf(aE[8 + j]);
                xo[j] = f2bf(aX[j]);
            }
            *(us8*)(T + (size_t)n * 512 + c16) = e0;      // EA over own P: safe
            *(us8*)(T + (size_t)n * 512 + c16 + 8) = e1;
            *(us8*)(XA + (size_t)n * 128 + c8) = xo;
        }
    }
    gridbar(flags, release, 3);

    // ========= phase 3: gemm2 (edges->T[0..127]) || gemm_node =========
    // unit u: u%3==0 -> gemm2 tile u/3; else gemm_node half (u%3-1) tile u/3.
    {
        const int u_total = row_tiles * 3;
        int it = 0;
        for (int u = blockIdx.x; u < u_total; u += nblk, ++it) {
            int tile = u / 3, kind = u - tile * 3;   // block-uniform
            int r0 = tile * 16;
            int arow = r0 + col16; if (arow >= N) arow = N - 1;
            unsigned short* sb = st[it & 1];
            int dstcol;
            if (kind == 0) {
                int col = wave * 16 + col16;          // 0..127
                short8 bf[8];
                for (int ks = 0; ks < 8; ++ks)
                    bf[ks] = *(const short8*)(WdT + (size_t)col * 256 + ks * 32 + quad * 8);
                f32x4 acc = {0.f, 0.f, 0.f, 0.f};
                const unsigned short* ap = T + (size_t)arow * 512 + quad * 8;
                for (int ks = 0; ks < 8; ++ks) {
                    short8 a = *(const short8*)(ap + ks * 32);
                    acc = __builtin_amdgcn_mfma_f32_16x16x32_bf16(a, bf[ks], acc, 0, 0, 0);
                }
                float bias = b_ed[col];
                for (int r = 0; r < 4; ++r)
                    sb[(quad * 4 + r) * 132 + col] = f2bf(fmaxf(acc[r] + bias, 0.f));
                dstcol = 0;                           // edges -> cols 0..127
            } else {
                int h = kind - 1;
                int lcol = wave * 16 + col16;
                int col = h * 128 + lcol;             // 0..255
                short8 bf[4];
                for (int ks = 0; ks < 4; ++ks)
                    bf[ks] = *(const short8*)(WnT + (size_t)col * 128 + ks * 32 + quad * 8);
                f32x4 acc = {0.f, 0.f, 0.f, 0.f};
                const unsigned short* ap = XA + (size_t)arow * 128 + quad * 8;
                for (int ks = 0; ks < 4; ++ks) {
                    short8 a = *(const short8*)(ap + ks * 32);
                    acc = __builtin_amdgcn_mfma_f32_16x16x32_bf16(a, bf[ks], acc, 0, 0, 0);
                }
                float bias = b_node[col];
                for (int r = 0; r < 4; ++r)
                    sb[(quad * 4 + r) * 132 + lcol] = f2bf(fmaxf(acc[r] + bias, 0.f));
                dstcol = 256 + h * 128;               // nodes -> cols 256..511
            }
            __syncthreads();
            if (r0 + srow < N) {
                us4 v = *(const us4*)(sb + srow * 132 + sc4);
                *(us4*)(T + (size_t)(r0 + srow) * 512 + dstcol + sc4) = v;
            }
        }
    }
    gridbar(flags, release, 4);

    // ================= phase 4: final MLP + sigmoid =================
    {
        for (int tile = blockIdx.x * 8 + wave; tile < row_tiles; tile += nblk * 8) {
            int r0 = tile * 16;
            int arow = r0 + col16; if (arow >= N) arow = N - 1;
            f32x4 acc0 = {0.f, 0.f, 0.f, 0.f}, acc1 = {0.f, 0.f, 0.f, 0.f};
            const unsigned short* ap = T + (size_t)arow * 512;
            const unsigned short* wpa = Wf1T + (size_t)col16 * 384;
            const unsigned short* wpb = Wf1T + (size_t)(col16 + 16) * 384;
            for (int ks = 0; ks < 12; ++ks) {
                int off = (ks < 8) ? 256 + ks * 32 : (ks - 8) * 32;  // nodes | edges
                short8 a = *(const short8*)(ap + off + quad * 8);
                short8 ba = *(const short8*)(wpa + ks * 32 + quad * 8);
                short8 bb = *(const short8*)(wpb + ks * 32 + quad * 8);
                acc0 = __builtin_amdgcn_mfma_f32_16x16x32_bf16(a, ba, acc0, 0, 0, 0);
                acc1 = __builtin_amdgcn_mfma_f32_16x16x32_bf16(a, bb, acc1, 0, 0, 0);
            }
            float f1a = b_f1[col16], f1b = b_f1[16 + col16];
            float w2a = W_f2[col16], w2b = W_f2[16 + col16];
            float b2 = b_f2[0];
            float s[4];
            for (int r = 0; r < 4; ++r)
                s[r] = fmaxf(acc0[r] + f1a, 0.f) * w2a + fmaxf(acc1[r] + f1b, 0.f) * w2b;
            for (int m = 1; m < 16; m <<= 1)
                for (int r = 0; r < 4; ++r) s[r] += __shfl_xor(s[r], m, 64);
            if (col16 == 0) {
                int orow = r0 + quad * 4;
                for (int r = 0; r < 4; ++r) {
                    if (orow + r < N) {
                        float v = s[r] + b2;
                        out[orow + r] = 1.f / (1.f + __expf(-v));
                    }
                }
            }
        }
    }
}

extern "C" void kernel_launch(void* const* d_in, const int* in_sizes, int n_in,
                              void* d_out, int out_size, void* d_ws, size_t ws_size,
                              hipStream_t stream) {
    const float* x      = (const float*)d_in[0];
    const int*   ei     = (const int*)d_in[1];
    // d_in[2] = e (unused)
    const float* W_node = (const float*)d_in[3];
    const float* b_node = (const float*)d_in[4];
    const float* W_edge = (const float*)d_in[5];
    const float* b_edge = (const float*)d_in[6];
    const float* W_ed   = (const float*)d_in[7];
    const float* b_ed   = (const float*)d_in[8];
    const float* W_f1   = (const float*)d_in[9];
    const float* b_f1   = (const float*)d_in[10];
    const float* W_f2   = (const float*)d_in[11];
    const float* b_f2   = (const float*)d_in[12];

    const int N = in_sizes[0] / 128;
    const int E = in_sizes[1] / 2;
    const int* src = ei;
    const int* dst = ei + E;

    char* ws = (char*)d_ws;
    size_t off = 0;
    auto alloc = [&](size_t bytes) { size_t o = off; off += (bytes + 255) & ~(size_t)255; return o; };
    unsigned short* xb   = (unsigned short*)(ws + alloc((size_t)N * 128 * 2));
    unsigned short* WE2T = (unsigned short*)(ws + alloc(512 * 128 * 2));
    unsigned short* WnT  = (unsigned short*)(ws + alloc(256 * 128 * 2));
    unsigned short* WdT  = (unsigned short*)(ws + alloc(128 * 256 * 2));
    unsigned short* Wf1T = (unsigned short*)(ws + alloc(32 * 384 * 2));
    unsigned short* T    = (unsigned short*)(ws + alloc((size_t)N * 512 * 2));
    unsigned short* XA   = (unsigned short*)(ws + alloc((size_t)N * 128 * 2));
    int* head            = (int*)(ws + alloc((size_t)N * 4));
    unsigned long long* next2 = (unsigned long long*)(ws + alloc((size_t)E * 8));
    int* flags           = (int*)(ws + alloc(512 * 4));
    int* release         = (int*)(ws + alloc(16));

    k_all<<<512, 512, 0, stream>>>(
        x, src, dst, W_node, b_node, W_edge, b_edge, W_ed, b_ed,
        W_f1, b_f1, W_f2, b_f2,
        xb, WE2T, WnT, WdT, Wf1T, T, XA, head, next2,
        flags, release, (float*)d_out, N, E);
}